// Round 14
// baseline (235.979 us; speedup 1.0000x reference)
//
#include <hip/hip_runtime.h>
#include <hip/hip_fp16.h>
#include <math.h>

#define N_NODES  50000
#define N_EDGES  800000
#define IN_F     128
#define HID_F    64
#define OUT_F    32
#define N_GRAPHS 128
#define SCAN_BLOCKS  ((N_NODES + 255) / 256)   // 196
#define GEMM_BLOCKS  ((N_NODES + 127) / 128)   // 391 (128 rows/block, 2 rows/thread)
#define HISTO_BLOCKS ((N_EDGES + 255) / 256)   // 3125
#define EPT 8                                  // edges per thread in fused kernel
                                               // 391*256*8 = 800,768 >= N_EDGES

// ---------------------------------------------------------------------------
// K1 (fused, interleaved): each block does BOTH a 128-row gemm tile AND 2048
// edges of the dst-histogram. Atomics are issued FIRST (independent, fire
// into the memory system), the FMA-dense gemm runs while they retire, and
// the returned positions are stored at the end. This converts the previous
// block-partition fusion (max-of-phases, imperfect) into true per-wave
// latency hiding; the memory-side atomic throughput (~40 us for 800k) now
// overlaps the ~25 us gemm instead of serializing past it.
__global__ __launch_bounds__(256) void fused_gemm_histo(const float* __restrict__ x,
                                                        const float* __restrict__ W,
                                                        __half* __restrict__ hs_h,
                                                        const int* __restrict__ dst,
                                                        int* __restrict__ cnt,
                                                        int* __restrict__ epos) {
    __shared__ float Ws[IN_F][HID_F];
    int tid   = threadIdx.x;
    int ebase = blockIdx.x * (256 * EPT) + tid;

    // --- issue histogram atomics early (coalesced dst reads, stride 256) ---
    int epv[EPT];
#pragma unroll
    for (int i = 0; i < EPT; ++i) {
        int e = ebase + i * 256;
        if (e < N_EDGES) epv[i] = atomicAdd(&cnt[dst[e]], 1);
    }

    // --- stage W to LDS (the vmcnt(0)+barrier here also absorbs the
    //     one-time atomic-return latency) ---
    for (int i = tid * 4; i < IN_F * HID_F; i += 256 * 4) {
        *(float4*)&((float*)Ws)[i] = *(const float4*)&W[i];
    }
    __syncthreads();

    // --- gemm: 2 rows/thread register-blocked ---
    int r0 = blockIdx.x * 128 + (tid >> 2);   // rows r0 and r0+64
    int r1 = r0 + 64;
    int c0 = (tid & 3) * 16;
    if (r0 < N_NODES) {
        bool has1 = (r1 < N_NODES);

        float acc0[16], acc1[16];
#pragma unroll
        for (int j = 0; j < 16; ++j) { acc0[j] = 0.0f; acc1[j] = 0.0f; }

        const float* xr0 = x + (size_t)r0 * IN_F;
        const float* xr1 = x + (size_t)r1 * IN_F;
        for (int k = 0; k < IN_F; k += 4) {
            float4 xa = *(const float4*)&xr0[k];
            float4 xb = has1 ? *(const float4*)&xr1[k] : make_float4(0, 0, 0, 0);
#pragma unroll
            for (int j = 0; j < 16; ++j) {
                float w0 = Ws[k + 0][c0 + j];
                float w1 = Ws[k + 1][c0 + j];
                float w2 = Ws[k + 2][c0 + j];
                float w3 = Ws[k + 3][c0 + j];
                acc0[j] += xa.x * w0 + xa.y * w1 + xa.z * w2 + xa.w * w3;
                acc1[j] += xb.x * w0 + xb.y * w1 + xb.z * w2 + xb.w * w3;
            }
        }
        __half* hr0 = hs_h + (size_t)r0 * HID_F + c0;
#pragma unroll
        for (int j = 0; j < 16; j += 2) {
            *(__half2*)&hr0[j] = __floats2half2_rn(acc0[j], acc0[j + 1]);
        }
        if (has1) {
            __half* hr1 = hs_h + (size_t)r1 * HID_F + c0;
#pragma unroll
            for (int j = 0; j < 16; j += 2) {
                *(__half2*)&hr1[j] = __floats2half2_rn(acc1[j], acc1[j + 1]);
            }
        }
    }

    // --- store the atomic-returned positions (coalesced) ---
#pragma unroll
    for (int i = 0; i < EPT; ++i) {
        int e = ebase + i * 256;
        if (e < N_EDGES) epos[e] = epv[i];
    }
}

// ---------------------------------------------------------------------------
// Hierarchical exclusive scan of cnt[50000] -> offsets[50000]
__global__ __launch_bounds__(256) void scan_partial_kernel(const int* __restrict__ cnt,
                                                           int* __restrict__ partials) {
    __shared__ int red[4];
    int i = blockIdx.x * 256 + threadIdx.x;
    int v = (i < N_NODES) ? cnt[i] : 0;
#pragma unroll
    for (int off = 32; off; off >>= 1) v += __shfl_down(v, off, 64);
    int w = threadIdx.x >> 6;
    if ((threadIdx.x & 63) == 0) red[w] = v;
    __syncthreads();
    if (threadIdx.x == 0) partials[blockIdx.x] = red[0] + red[1] + red[2] + red[3];
}

__global__ __launch_bounds__(256) void scan_top_kernel(const int* __restrict__ partials,
                                                       int* __restrict__ ppref) {
    __shared__ int buf[256];
    int t = threadIdx.x;
    buf[t] = (t < SCAN_BLOCKS) ? partials[t] : 0;
    __syncthreads();
    for (int off = 1; off < 256; off <<= 1) {
        int v = (t >= off) ? buf[t - off] : 0;
        __syncthreads();
        buf[t] += v;
        __syncthreads();
    }
    if (t < SCAN_BLOCKS) ppref[t] = (t > 0) ? buf[t - 1] : 0;
}

__global__ __launch_bounds__(256) void scan_final_kernel(const int* __restrict__ cnt,
                                                         const int* __restrict__ ppref,
                                                         int* __restrict__ offsets) {
    __shared__ int buf[256];
    int t = threadIdx.x;
    int i = blockIdx.x * 256 + t;
    int v = (i < N_NODES) ? cnt[i] : 0;
    buf[t] = v;
    __syncthreads();
    for (int off = 1; off < 256; off <<= 1) {
        int x = (t >= off) ? buf[t - off] : 0;
        __syncthreads();
        buf[t] += x;
        __syncthreads();
    }
    if (i < N_NODES) offsets[i] = ppref[blockIdx.x] + buf[t] - v;
}

// ---------------------------------------------------------------------------
// K3: bucket edges by dst — atomic-free (positions precomputed in histo).
__global__ __launch_bounds__(256) void bucket_kernel(const int* __restrict__ src,
                                                     const int* __restrict__ dst,
                                                     const float* __restrict__ ew,
                                                     const int* __restrict__ epos,
                                                     const int* __restrict__ offsets,
                                                     int2* __restrict__ edat) {
    int e = blockIdx.x * 256 + threadIdx.x;
    if (e < N_EDGES) {
        int d   = dst[e];
        int pos = offsets[d] + epos[e];
        edat[pos] = make_int2(src[e], __float_as_int(ew[e]));
    }
}

// K4: weighted degree from bucketed CSR -> dinv = 1/sqrt(1+sum)
__global__ __launch_bounds__(256) void degw_kernel(const int* __restrict__ offsets,
                                                   const int* __restrict__ cnt,
                                                   const int2* __restrict__ edat,
                                                   float* __restrict__ dinv) {
    int n = blockIdx.x * 256 + threadIdx.x;
    if (n >= N_NODES) return;
    int beg = offsets[n], end = beg + cnt[n];
    float s = 1.0f;                               // self-loop weight
    for (int j = beg; j < end; ++j) s += __int_as_float(edat[j].y);
    dinv[n] = 1.0f / sqrtf(s);
}

// K5: per-node gather-reduce + self-loop + bias + tanh.
// One wave per node. Lane layout: lane = half*32 + fl; lane holds feature
// pair {2fl, 2fl+1} as __half2 (one dword). lo half processes even-offset
// edges, hi half odd-offset; 2-way unroll -> 4 outstanding gathers/wave.
__global__ __launch_bounds__(256) void aggregate_kernel(const __half* __restrict__ hs_h,
                                                        const int* __restrict__ offsets,
                                                        const int* __restrict__ cnt,
                                                        const int2* __restrict__ edat,
                                                        const float* __restrict__ dinv,
                                                        const float* __restrict__ b,
                                                        float* __restrict__ nout) {
    int node = blockIdx.x * 4 + (threadIdx.x >> 6);
    if (node >= N_NODES) return;
    int lane = threadIdx.x & 63;
    int half = lane >> 5;        // 0: even-offset edges, 1: odd-offset
    int fl   = lane & 31;        // feature pair index
    int beg  = offsets[node];
    int end  = beg + cnt[node];

    float ax0 = 0.0f, ay0 = 0.0f, ax1 = 0.0f, ay1 = 0.0f;
    int j = beg + half;
    for (; j + 2 < end; j += 4) {                 // edges j and j+2 (this half)
        int2 e0 = edat[j];
        int2 e1 = edat[j + 2];
        float w0 = dinv[e0.x] * __int_as_float(e0.y);
        float w1 = dinv[e1.x] * __int_as_float(e1.y);
        float2 h0 = __half22float2(*(const __half2*)&hs_h[(size_t)e0.x * HID_F + 2 * fl]);
        float2 h1 = __half22float2(*(const __half2*)&hs_h[(size_t)e1.x * HID_F + 2 * fl]);
        ax0 += h0.x * w0; ay0 += h0.y * w0;
        ax1 += h1.x * w1; ay1 += h1.y * w1;
    }
    if (j < end) {                                // at most one edge left/half
        int2 e0 = edat[j];
        float w0 = dinv[e0.x] * __int_as_float(e0.y);
        float2 h0 = __half22float2(*(const __half2*)&hs_h[(size_t)e0.x * HID_F + 2 * fl]);
        ax0 += h0.x * w0; ay0 += h0.y * w0;
    }

    float sx = ax0 + ax1;
    float sy = ay0 + ay1;
    // merge the two halves: lane L gets lane L^32's partial
    sx += __shfl_xor(sx, 32, 64);
    sy += __shfl_xor(sy, 32, 64);

    if (half == 0) {
        float dn = dinv[node];
        float2 hself = __half22float2(*(const __half2*)&hs_h[(size_t)node * HID_F + 2 * fl]);
        float2 bb = *(const float2*)&b[2 * fl];
        float vx = dn * (sx + hself.x * dn) + bb.x;
        float vy = dn * (sy + hself.y * dn) + bb.y;
        *(float2*)&nout[(size_t)node * HID_F + 2 * fl] = make_float2(tanhf(vx), tanhf(vy));
    }
}

// K6: per-graph mean-pool + [64->32] GEMM + tanh, with inlined graph-bounds
// binary search (removes the separate bounds_kernel dispatch).
__global__ __launch_bounds__(256) void pool_kernel(const float* __restrict__ ne,
                                                   const int* __restrict__ batch,
                                                   const float* __restrict__ W1,
                                                   const float* __restrict__ b1,
                                                   float* __restrict__ gout) {
    __shared__ float part[4][HID_F];
    __shared__ float mean_s[HID_F];
    __shared__ int   range_s[2];
    int g = blockIdx.x;

    // threads 0/1 binary-search lo/hi bound of this graph's node range
    if (threadIdx.x < 2) {
        int target = g + threadIdx.x;            // lower_bound(batch, target)
        int lo = 0, hi = N_NODES;
        while (lo < hi) {
            int m = (lo + hi) >> 1;
            if (batch[m] < target) lo = m + 1; else hi = m;
        }
        range_s[threadIdx.x] = lo;
    }
    __syncthreads();
    int lo = range_s[0], hi = range_s[1];

    int f = threadIdx.x & 63;
    int w = threadIdx.x >> 6;

    float s = 0.0f;
    for (int i = lo + w; i < hi; i += 4) s += ne[(size_t)i * HID_F + f];
    part[w][f] = s;
    __syncthreads();

    if (w == 0) {
        float m   = part[0][f] + part[1][f] + part[2][f] + part[3][f];
        float cnt = (float)(hi - lo);
        mean_s[f] = m / fmaxf(cnt, 1.0f);
    }
    __syncthreads();

    int o = threadIdx.x;
    if (o < OUT_F) {
        float acc = b1[o];
        for (int k = 0; k < HID_F; ++k) acc += mean_s[k] * W1[k * OUT_F + o];
        gout[(size_t)g * OUT_F + o] = tanhf(acc);
    }
}

extern "C" void kernel_launch(void* const* d_in, const int* in_sizes, int n_in,
                              void* d_out, int out_size, void* d_ws, size_t ws_size,
                              hipStream_t stream) {
    const float* x   = (const float*)d_in[0];
    const int*   ei  = (const int*)d_in[1];          // [2][E]: src row then dst row
    const float* ew  = (const float*)d_in[2];
    const int*   bat = (const int*)d_in[3];
    const float* W   = (const float*)d_in[5];
    const float* b   = (const float*)d_in[6];
    const float* W1  = (const float*)d_in[7];
    const float* b1  = (const float*)d_in[8];

    const int* src = ei;
    const int* dst = ei + N_EDGES;

    float* gout = (float*)d_out;
    float* nout = (float*)d_out + (size_t)N_GRAPHS * OUT_F;

    // Workspace layout (float words):
    // dinv[50k] | hs_h[1.6M words = 3.2M halves] | cnt[50k]i | offsets[50k]i |
    // partials[256]i | ppref[256]i | epos[800k]i | edat[800k]int2
    float*  ws_f     = (float*)d_ws;
    float*  dinv     = ws_f;                        // 50,000
    __half* hs_h     = (__half*)(ws_f + 50000);     // 3,200,000 halves
    int*    cnt      = (int*)(ws_f + 1650000);      // 50,000
    int*    offsets  = (int*)(ws_f + 1700000);      // 50,000
    int*    partials = (int*)(ws_f + 1750000);      // 256
    int*    ppref    = (int*)(ws_f + 1750256);      // 256
    int*    epos     = (int*)(ws_f + 1750512);      // 800,000
    int2*   edat     = (int2*)(ws_f + 2550512);     // 800,000 int2 (8B-aligned)

    // zero cnt (200 KB) — ws is re-poisoned before each call
    hipMemsetAsync(cnt, 0, (size_t)N_NODES * sizeof(int), stream);

    fused_gemm_histo<<<GEMM_BLOCKS, 256, 0, stream>>>(x, W, hs_h, dst, cnt, epos);

    scan_partial_kernel<<<SCAN_BLOCKS, 256, 0, stream>>>(cnt, partials);
    scan_top_kernel<<<1, 256, 0, stream>>>(partials, ppref);
    scan_final_kernel<<<SCAN_BLOCKS, 256, 0, stream>>>(cnt, ppref, offsets);

    bucket_kernel<<<HISTO_BLOCKS, 256, 0, stream>>>(src, dst, ew, epos,
                                                    offsets, edat);

    degw_kernel<<<SCAN_BLOCKS, 256, 0, stream>>>(offsets, cnt, edat, dinv);

    aggregate_kernel<<<(N_NODES + 3) / 4, 256, 0, stream>>>(hs_h, offsets, cnt, edat,
                                                            dinv, b, nout);

    pool_kernel<<<N_GRAPHS, 256, 0, stream>>>(nout, bat, W1, b1, gout);
}